// Round 18
// baseline (231.766 us; speedup 1.0000x reference)
//
#include <hip/hip_runtime.h>
#include <hip/hip_bf16.h>
#include <stdint.h>

#define BB 8
#define NN 2048

// ---- workspace layout ----
#define OFF_B1 272
#define OFF_B2 4432
#define OFF_B3 12688
#define IDX_BYTE_OFF 65536            // u16 idx[B][N][64] = 2 MiB (65536..2162688)
#define T_BASE   (65536 + 2*1024*1024)
// fragment-linear weight tables: lane L's 16B MFMA A-fragment at base + L*16 (conflict-free)
#define T1_OFF   T_BASE               // [4 tiles][64 lanes][8] bf16 = 4096 B
#define T2H_OFF  (T1_OFF + 4096)      // [4mt*2g][64][8] bf16 = 8192 B
#define T2L_OFF  (T2H_OFF + 8192)
#define T3H_OFF  (T2L_OFF + 8192)     // [8mt*2g][64][8] bf16 = 16384 B
#define T3L_OFF  (T3H_OFF + 16384)    // tables end at T_BASE+53248 = 2215936
#define XYZ_OFF  2228224              // f32x4 xyzs2[2][8][2048] = 512 KiB (built by k1 tail blocks)
// LDS element-offsets (uint16) for k2's staged copy
#define L_T1   0
#define L_T2H  2048
#define L_T2L  6144
#define L_T3H  10240
#define L_T3L  18432
#define L_ELEMS 26624                 // 53248 B = 3328 uint4

typedef __attribute__((ext_vector_type(4))) float f32x4;
typedef __attribute__((ext_vector_type(8))) short s16x8;

__device__ __forceinline__ float ldany(const void* p, long i, int isf32) {
    if (isf32) return ((const float*)p)[i];
    uint32_t u = ((uint32_t)((const uint16_t*)p)[i]) << 16;
    float f; __builtin_memcpy(&f, &u, 4); return f;
}
__device__ __forceinline__ uint16_t f2bf(float f) {
    uint32_t u; __builtin_memcpy(&u, &f, 4);
    return (uint16_t)((u + 0x7FFFu + ((u >> 16) & 1u)) >> 16);
}
__device__ __forceinline__ float bf2f(uint16_t h) {
    uint32_t u = ((uint32_t)h) << 16;
    float f; __builtin_memcpy(&f, &u, 4); return f;
}
__device__ __forceinline__ uint32_t pk2(float a, float b) {
    __hip_bfloat162 h = __float22bfloat162_rn(make_float2(a, b));
    uint32_t u; __builtin_memcpy(&u, &h, 4); return u;
}
__device__ __forceinline__ s16x8 mk8(uint32_t a, uint32_t b, uint32_t c, uint32_t d) {
    uint32_t t[4] = {a, b, c, d}; s16x8 r; __builtin_memcpy(&r, t, 16); return r;
}
__device__ __forceinline__ float sane(float v) {
    return (v == v && v > -1e30f && v < 1e30f) ? v : 0.f;
}
__device__ __forceinline__ int mbcnt64(unsigned long long m) {
    return __builtin_amdgcn_mbcnt_hi((uint32_t)(m >> 32),
           __builtin_amdgcn_mbcnt_lo((uint32_t)m, 0));
}
__device__ __forceinline__ int kperm_pos(int kk) {
    int g = kk >> 5, c5 = kk & 31;
    int sub = (c5 >> 4) & 1, q = (c5 >> 2) & 3, r = c5 & 3;
    return 32 * g + 8 * q + 4 * sub + r;
}
// fragment-linear position for a (row o, within-row pos p) element of a 16-row-tile table.
__device__ __forceinline__ int fraglin(int o, int p) {
    int g = p >> 5, q = (p >> 3) & 3, e = p & 7;
    return ((((o >> 4) * 2 + g) * 64) + q * 16 + (o & 15)) * 8 + e;
}
// T1 (single 32-col table)
__device__ __forceinline__ int fraglin1(int o, int col) {
    int q = col >> 3, e = col & 7;
    return (((o >> 4) * 64) + q * 16 + (o & 15)) * 8 + e;
}

// ---------------- fallback-only: 1-block device dtype detect (used iff in_sizes is ambiguous) ----------------
__global__ void kdetect(const void* p1, int* wsi) {
    __shared__ int s_cnt;
    int t = threadIdx.x;
    if (t == 0) s_cnt = 0;
    __syncthreads();
    const uint16_t* u = (const uint16_t*)p1;
    int c = 0;
    for (int i = t; i < 4096; i += 256) {
        uint16_t x = u[i];
        uint32_t e = (x >> 7) & 0xFF;
        c += ((e >= 0x70 && e <= 0x84) || x == 0) ? 1 : 0;
    }
    atomicAdd(&s_cnt, c);
    __syncthreads();
    if (t == 0) wsi[0] = (s_cnt < 3686) ? 1 : 0;
}

// ---- fold body: executed by blocks 0..54 of k1 as a cold tail ----
__device__ __forceinline__ void do_fold(int gid, int isf32,
                        const void* W1, const void* b1, const void* g1, const void* be1, const void* m1, const void* v1,
                        const void* W2, const void* b2, const void* g2, const void* be2, const void* m2, const void* v2,
                        const void* W3, const void* b3, const void* g3, const void* be3, const void* m3, const void* v3,
                        float* wsf) {
    uint16_t* t1  = (uint16_t*)((char*)wsf + T1_OFF);
    uint16_t* t2h = (uint16_t*)((char*)wsf + T2H_OFF);
    uint16_t* t2l = (uint16_t*)((char*)wsf + T2L_OFF);
    uint16_t* t3h = (uint16_t*)((char*)wsf + T3H_OFF);
    uint16_t* t3l = (uint16_t*)((char*)wsf + T3L_OFF);

    if (gid < 4096) {
        int o = gid >> 6, kk = gid & 63;
        float s = ldany(g2, o, isf32) * rsqrtf(ldany(v2, o, isf32) + 1e-3f);
        float w = ldany(W2, gid, isf32) * s;
        uint16_t wh = f2bf(w);
        int pos = fraglin(o, kperm_pos(kk));
        t2h[pos] = wh; t2l[pos] = f2bf(w - bf2f(wh));
    } else if (gid < 12288) {
        int e = gid - 4096;
        int o = e >> 6, kk = e & 63;
        float s = ldany(g3, o, isf32) * rsqrtf(ldany(v3, o, isf32) + 1e-3f);
        float w = ldany(W3, e, isf32) * s;
        uint16_t wh = f2bf(w);
        int pos = fraglin(o, kperm_pos(kk));
        t3h[pos] = wh; t3l[pos] = f2bf(w - bf2f(wh));
    } else if (gid < 12544) {
        int e = gid - 12288;
        int co = e >> 2, cc = e & 3;
        float s = ldany(g1, co, isf32) * rsqrtf(ldany(v1, co, isf32) + 1e-3f);
        float w = ldany(W1, co*4 + cc, isf32) * s;
        uint16_t wh = f2bf(w), wl = f2bf(w - bf2f(wh));
        t1[fraglin1(co, cc)]     = wh;
        t1[fraglin1(co, 4 + cc)] = wh;
        t1[fraglin1(co, 8 + cc)] = wl;
    } else if (gid < 13824) {
        int e = gid - 12544;
        int co = e / 20, k = e - co * 20;
        t1[fraglin1(co, 12 + k)] = 0;
    } else if (gid < 13888) {
        int o = gid - 13824;
        float s = ldany(g1, o, isf32) * rsqrtf(ldany(v1, o, isf32) + 1e-3f);
        wsf[OFF_B1 + o] = (ldany(b1, o, isf32) - ldany(m1, o, isf32)) * s + ldany(be1, o, isf32);
    } else if (gid < 13952) {
        int o = gid - 13888;
        float s = ldany(g2, o, isf32) * rsqrtf(ldany(v2, o, isf32) + 1e-3f);
        wsf[OFF_B2 + o] = (ldany(b2, o, isf32) - ldany(m2, o, isf32)) * s + ldany(be2, o, isf32);
    } else if (gid < 14080) {
        int o = gid - 13952;
        float s = ldany(g3, o, isf32) * rsqrtf(ldany(v3, o, isf32) + 1e-3f);
        wsf[OFF_B3 + o] = (ldany(b3, o, isf32) - ldany(m3, o, isf32)) * s + ldany(be3, o, isf32);
    }
}

// ---- one-target exact top-32 from an LDS-staged table (R17-proven) ----
__device__ __forceinline__ void knn_target(const f32x4* __restrict__ tb, int lane,
                                           float qx, float qy, float qz, float s1,
                                           unsigned long long* sl, uint16_t* dst) {
    uint32_t kb[32];
    #pragma unroll
    for (int i = 0; i < 32; i++) {
        f32x4 P = tb[i * 64 + lane];
        float dot = qx * P[0] + qy * P[1] + qz * P[2];
        float d2  = fmaxf((s1 + P[3]) - 2.0f * dot, 0.0f);
        uint32_t bits; __builtin_memcpy(&bits, &d2, 4);
        kb[i] = bits;
    }

    // coarse: windowed bisection with interpolated probes, accept count in [32,64].
    uint32_t lo = 0u, hi = 0x7F800001u, tau = 0u;
    uint32_t mid = 0x3E800000u;   // 0.25f
    while (true) {
        int c = 0;
        #pragma unroll
        for (int i = 0; i < 32; i++) c += __builtin_popcountll(__ballot(kb[i] < mid));
        if (c >= 32 && c <= 64) { tau = mid; break; }
        if (c < 32) lo = mid; else hi = mid;
        if (hi - lo <= 1u) { tau = hi; break; }
        float mf; __builtin_memcpy(&mf, &mid, 4);
        float nf = mf * __powf(48.0f / (float)(c < 1 ? 1 : c), 0.6666667f);
        uint32_t nm; __builtin_memcpy(&nm, &nf, 4);
        if (!(nm > lo && nm < hi)) nm = lo + ((hi - lo) >> 1);
        mid = nm;
    }

    // compaction of survivors (kb < tau) into 64 LDS slots, key = (d2<<32)|idx
    sl[lane] = ~0ull;
    int basePos = 0;
    #pragma unroll
    for (int i = 0; i < 32; i++) {
        unsigned idxv = (unsigned)(i * 64 + lane);   // linear scan order (unified dtypes)
        bool pz = kb[i] < tau;
        unsigned long long m = __ballot(pz);
        int pos = basePos + mbcnt64(m);
        if (pz && pos < 64) sl[pos] = (((unsigned long long)kb[i]) << 32) | idxv;
        basePos += __builtin_popcountll(m);
    }
    unsigned long long key = sl[lane];

    // fine: single-ballot bisection for m* with |{key < m*}| == 32 exactly.
    int ns = basePos > 64 ? 64 : basePos;     // survivors actually in slots (>=32)
    unsigned long long mstar = ~0ull;         // ns==32: survivors ARE the set; skip fine
    if (ns != 32) {
        unsigned long long flo = 0ull;
        unsigned long long fhi = (((unsigned long long)tau) << 32) + 2048ull;
        float tauf; uint32_t tb2 = tau; __builtin_memcpy(&tauf, &tb2, 4);
        float g = tauf * __powf(32.5f / (float)ns, 0.6666667f);
        uint32_t gb; __builtin_memcpy(&gb, &g, 4);
        unsigned long long m0 = ((unsigned long long)gb) << 32;
        if (!(m0 > flo && m0 < fhi)) m0 = flo + ((fhi - flo) >> 1);
        unsigned long long midk = m0;
        while (true) {
            int f = __builtin_popcountll(__ballot(key < midk));
            if (f == 32) { mstar = midk; break; }
            if (f < 32) flo = midk; else fhi = midk;
            if (fhi - flo <= 1ull) { mstar = fhi; break; }
            midk = flo + ((fhi - flo) >> 1);
        }
    }

    bool sel = key < mstar;
    unsigned long long sm = __ballot(sel);
    if (sel) dst[mbcnt64(sm)] = (uint16_t)(key & 0x7FFu);
}

// ---------------- K1: dual-target top-32 — LDS table staged DIRECTLY from p1/p2 (k0_xyz absorbed);
// cold tails: blocks 0..54 fold params, blocks 55..182 build the global xyz table for k2. ----
__launch_bounds__(256)
__global__ void k1_knn(const void* p1, const void* p2,
                       const void* W1, const void* b1, const void* g1, const void* be1, const void* m1, const void* v1,
                       const void* W2, const void* b2, const void* g2, const void* be2, const void* m2, const void* v2,
                       const void* W3, const void* b3, const void* g3, const void* be3, const void* m3, const void* v3,
                       float* wsf, const int* wsi, uint16_t* idxout, int isf32arg) {
    __shared__ f32x4 stab[2048];                    // 32 KB staged table (one target at a time)
    __shared__ unsigned long long smem[4 * 64];     // per-wave compaction slots

    int isf32 = (isf32arg >= 0) ? isf32arg : wsi[0];

    int t = threadIdx.x;
    int lane = threadIdx.x & 63;
    int wave = threadIdx.x >> 6;
    int qidx = blockIdx.x * 4 + wave;
    int b = qidx >> 11, n = qidx & 2047;            // 512 blocks/batch: all 4 waves share b
    long bb = (long)b * 3 * NN;

    // query: identical expressions to the old k0_xyz (bit-identical values)
    float qx = ldany(p1, bb + n,        isf32);
    float qy = ldany(p1, bb + NN + n,   isf32);
    float qz = ldany(p1, bb + 2*NN + n, isf32);
    float s1 = qx * qx + qy * qy + qz * qz;

    unsigned long long* sl = smem + wave * 64;
    long obase = ((long)qidx) << 6;

    // stage target 1 directly from p1 (convert + s2, same expressions as k0_xyz)
    for (int j = t; j < 2048; j += 256) {
        float x = ldany(p1, bb + j,        isf32);
        float y = ldany(p1, bb + NN + j,   isf32);
        float z = ldany(p1, bb + 2*NN + j, isf32);
        f32x4 v; v[0] = x; v[1] = y; v[2] = z; v[3] = x * x + y * y + z * z;
        stab[j] = v;
    }
    __syncthreads();
    knn_target(stab, lane, qx, qy, qz, s1, sl, idxout + obase);
    __syncthreads();

    // stage target 2 from p2
    for (int j = t; j < 2048; j += 256) {
        float x = ldany(p2, bb + j,        isf32);
        float y = ldany(p2, bb + NN + j,   isf32);
        float z = ldany(p2, bb + 2*NN + j, isf32);
        f32x4 v; v[0] = x; v[1] = y; v[2] = z; v[3] = x * x + y * y + z * z;
        stab[j] = v;
    }
    __syncthreads();
    knn_target(stab, lane, qx, qy, qz, s1, sl, idxout + obase + 32);

    // cold tails (no live state carried in):
    if (blockIdx.x < 55) {
        // parameter fold (identical gid mapping)
        int gid = blockIdx.x * 256 + t;
        do_fold(gid, isf32,
                W1, b1, g1, be1, m1, v1,
                W2, b2, g2, be2, m2, v2,
                W3, b3, g3, be3, m3, v3, wsf);
    } else if (blockIdx.x < 183) {
        // build global AoS xyz table for k2 (identical expressions to old k0_xyz)
        int gid = (blockIdx.x - 55) * 256 + t;       // 0..32767
        int tgt = gid >> 14, rem = gid & 16383;
        int b2i = rem >> 11, n2 = rem & 2047;
        const void* pp = tgt ? p2 : p1;
        long bbase = (long)b2i * 3 * NN;
        float x = ldany(pp, bbase + n2,        isf32);
        float y = ldany(pp, bbase + NN + n2,   isf32);
        float z = ldany(pp, bbase + 2*NN + n2, isf32);
        f32x4 v; v[0] = x; v[1] = y; v[2] = z; v[3] = x * x + y * y + z * z;
        ((f32x4*)((char*)wsf + XYZ_OFF))[gid] = v;
    }
}

// ---------------- K2: MFMA MLP — streaming conversion (R10-proven), frag-linear LDS, (512,2);
// neighbor/query coords gathered from the AoS table (built by k1's tail blocks) ----
__launch_bounds__(512, 2)
__global__ void k2_mlp(const float* __restrict__ wsf, const int* wsi,
                       const uint16_t* __restrict__ idxin, void* outp, int isf32arg) {
    __shared__ uint4 shw4[L_ELEMS / 8];

    {
        const uint4* src = (const uint4*)((const char*)wsf + T1_OFF);
        for (int i = threadIdx.x; i < L_ELEMS / 8; i += 512) shw4[i] = src[i];
    }
    __syncthreads();
    const uint16_t* shw = (const uint16_t*)shw4;
    const uint16_t* T1  = shw + L_T1;
    const uint16_t* T2H = shw + L_T2H;
    const uint16_t* T2L = shw + L_T2L;
    const uint16_t* T3H = shw + L_T3H;
    const uint16_t* T3L = shw + L_T3L;

    int isf32 = (isf32arg >= 0) ? isf32arg : wsi[0];
    int lane = threadIdx.x & 63;
    int wave = threadIdx.x >> 6;        // 0..7
    int c = lane & 15;
    int q = lane >> 4;
    int qidx = blockIdx.x * 8 + wave;   // 2048 blocks x 8 waves = 16384 queries
    int b = qidx >> 11, n = qidx & 2047;
    long base = (long)b * 3 * NN;

    const f32x4* xyz = (const f32x4*)((const char*)wsf + XYZ_OFF);

    f32x4 Q = xyz[(long)b * NN + n];
    float qx = sane(Q[0]), qy = sane(Q[1]), qz = sane(Q[2]);

    int idx = idxin[((long)qidx << 6) + lane] & 2047;
    int tgt = (lane < 32) ? 0 : 1;
    f32x4 P = xyz[(long)(tgt * 8 + b) * NN + idx];
    float nx = sane(P[0]), ny = sane(P[1]), nz = sane(P[2]);

    float r0 = nx - qx, r1 = ny - qy, r2 = nz - qz;
    float ss = fmaf(r0, r0, fmaf(r1, r1, r2 * r2));
    float dist = sqrtf(fmaxf(ss, 1e-12f));

    const float* B1 = wsf + OFF_B1;
    const float* B2 = wsf + OFF_B2;
    const float* B3 = wsf + OFF_B3;

    auto mkfrag = [](const f32x4& dlo, const f32x4& dhi) -> s16x8 {
        return mk8(pk2(fmaxf(dlo[0], 0.f), fmaxf(dlo[1], 0.f)),
                   pk2(fmaxf(dlo[2], 0.f), fmaxf(dlo[3], 0.f)),
                   pk2(fmaxf(dhi[0], 0.f), fmaxf(dhi[1], 0.f)),
                   pk2(fmaxf(dhi[2], 0.f), fmaxf(dhi[3], 0.f)));
    };

    // ---- layer 1: b1f (16 VGPR) + d1[4][4] (64) live; then convert ALL to fh (32), d1 dies ----
    s16x8 b1f[4];
    #pragma unroll
    for (int nt = 0; nt < 4; nt++) {
        int src = 16 * nt + c;
        float f0 = __shfl(r0, src, 64);
        float f1 = __shfl(r1, src, 64);
        float f2v = __shfl(r2, src, 64);
        float f3v = __shfl(dist, src, 64);
        uint16_t h0 = f2bf(f0), h1 = f2bf(f1), h2 = f2bf(f2v), h3 = f2bf(f3v);
        uint16_t l0 = f2bf(f0 - bf2f(h0)), l1 = f2bf(f1 - bf2f(h1));
        uint16_t l2 = f2bf(f2v - bf2f(h2)), l3 = f2bf(f3v - bf2f(h3));
        s16x8 v;
        bool qa = (q < 2);
        bool qb = (q == 0);
        v[0] = qa ? (short)h0 : (short)0;
        v[1] = qa ? (short)h1 : (short)0;
        v[2] = qa ? (short)h2 : (short)0;
        v[3] = qa ? (short)h3 : (short)0;
        v[4] = qb ? (short)l0 : (short)0;
        v[5] = qb ? (short)l1 : (short)0;
        v[6] = qb ? (short)l2 : (short)0;
        v[7] = qb ? (short)l3 : (short)0;
        b1f[nt] = v;
    }

    s16x8 fh[2][4];
    {
        f32x4 d1[4][4];
        #pragma unroll
        for (int mt = 0; mt < 4; mt++) {
            s16x8 a1 = *(const s16x8*)(T1 + (mt * 64 + lane) * 8);
            f32x4 bias = *(const f32x4*)(B1 + 16 * mt + 4 * q);
            #pragma unroll
            for (int nt = 0; nt < 4; nt++) {
                d1[mt][nt] = __builtin_amdgcn_mfma_f32_16x16x32_bf16(a1, b1f[nt], bias, 0, 0, 0);
            }
        }
        #pragma unroll
        for (int g = 0; g < 2; g++)
            #pragma unroll
            for (int nt = 0; nt < 4; nt++) fh[g][nt] = mkfrag(d1[2*g][nt], d1[2*g+1][nt]);
    }

    // ---- layer 2: fh (32) + d2[4][4] (64) + one weight pair (8) live ----
    s16x8 f3h[2][4];
    {
        f32x4 d2[4][4];
        #pragma unroll
        for (int mt = 0; mt < 4; mt++) {
            f32x4 bias = *(const f32x4*)(B2 + 16 * mt + 4 * q);
            #pragma unroll
            for (int nt = 0; nt < 4; nt++) d2[mt][nt] = bias;
        }
        #pragma unroll
        for (int g = 0; g < 2; g++) {
            #pragma unroll
            for (int mt = 0; mt < 4; mt++) {
                s16x8 ah = *(const s16x8*)(T2H + ((mt * 2 + g) * 64 + lane) * 8);
                s16x8 al = *(const s16x8*)(T2L + ((mt * 2 + g) * 64 + lane) * 8);
                #pragma unroll
                for (int nt = 0; nt < 4; nt++) {
                    f32x4 acc = d2[mt][nt];
                    acc = __builtin_amdgcn_mfma_f32_16x16x32_bf16(ah, fh[g][nt], acc, 0, 0, 0);
                    acc = __builtin_amdgcn_mfma_f32_16x16x32_bf16(al, fh[g][nt], acc, 0, 0, 0);
                    d2[mt][nt] = acc;
                }
            }
        }
        #pragma unroll
        for (int g = 0; g < 2; g++)
            #pragma unroll
            for (int nt = 0; nt < 4; nt++) f3h[g][nt] = mkfrag(d2[2*g][nt], d2[2*g+1][nt]);
    }

    // ---- layer 3: f3h (32) + acc[4] (16) + mx (4) live ----
    float mx[4] = {-1e30f, -1e30f, -1e30f, -1e30f};
    #pragma unroll
    for (int mt = 0; mt < 8; mt++) {
        f32x4 bias = *(const f32x4*)(B3 + 16 * mt + 4 * q);
        f32x4 acc[4];
        #pragma unroll
        for (int nt = 0; nt < 4; nt++) acc[nt] = bias;
        #pragma unroll
        for (int g = 0; g < 2; g++) {
            s16x8 ah = *(const s16x8*)(T3H + ((mt * 2 + g) * 64 + lane) * 8);
            s16x8 al = *(const s16x8*)(T3L + ((mt * 2 + g) * 64 + lane) * 8);
            #pragma unroll
            for (int nt = 0; nt < 4; nt++) {
                f32x4 a = acc[nt];
                a = __builtin_amdgcn_mfma_f32_16x16x32_bf16(ah, f3h[g][nt], a, 0, 0, 0);
                a = __builtin_amdgcn_mfma_f32_16x16x32_bf16(al, f3h[g][nt], a, 0, 0, 0);
                acc[nt] = a;
            }
        }
        #pragma unroll
        for (int nt = 0; nt < 4; nt++) {
            mx[nt] = fmaxf(mx[nt], fmaxf(fmaxf(acc[nt][0], acc[nt][1]), fmaxf(acc[nt][2], acc[nt][3])));
        }
    }

    #pragma unroll
    for (int nt = 0; nt < 4; nt++) {
        mx[nt] = fmaxf(mx[nt], __shfl_xor(mx[nt], 16, 64));
        mx[nt] = fmaxf(mx[nt], __shfl_xor(mx[nt], 32, 64));
        mx[nt] = fmaxf(mx[nt], 0.f);
    }
    float mall = fmaxf(fmaxf(mx[0], mx[1]), fmaxf(mx[2], mx[3]));
    #pragma unroll
    for (int m = 1; m < 16; m <<= 1) mall = fmaxf(mall, __shfl_xor(mall, m, 64));
    float e0 = __expf(mx[0] - mall), e1 = __expf(mx[1] - mall);
    float e2 = __expf(mx[2] - mall), e3 = __expf(mx[3] - mall);
    float s = e0 + e1 + e2 + e3;
    #pragma unroll
    for (int m = 1; m < 16; m <<= 1) s += __shfl_xor(s, m, 64);
    float eown = (q == 0) ? e0 : (q == 1) ? e1 : (q == 2) ? e2 : e3;
    float w = eown / s;

    float sx = w * nx, sy = w * ny, sz = w * nz;
    #pragma unroll
    for (int m = 1; m < 64; m <<= 1) {
        sx += __shfl_xor(sx, m, 64);
        sy += __shfl_xor(sy, m, 64);
        sz += __shfl_xor(sz, m, 64);
    }

    if (lane < 3) {
        float v = (lane == 0) ? sx : ((lane == 1) ? sy : sz);
        long oi = base + (long)lane * NN + n;
        if (isf32) {
            ((float*)outp)[oi] = v;
        } else {
            ((uint16_t*)outp)[oi] = f2bf(v);
        }
    }
}

extern "C" void kernel_launch(void* const* d_in, const int* in_sizes, int n_in,
                              void* d_out, int out_size, void* d_ws, size_t ws_size,
                              hipStream_t stream) {
    const void* p1 = d_in[0];
    const void* p2 = d_in[1];
    float* wsf = (float*)d_ws;
    int*   wsi = (int*)d_ws;
    uint16_t* idxbuf = (uint16_t*)((char*)d_ws + IDX_BYTE_OFF);

    // host-side dtype resolution from buffer byte sizes; -1 => device-detect fallback
    int isf32 = -1;
    if (in_sizes && n_in >= 1) {
        if (in_sizes[0] == BB * 3 * NN * 4)      isf32 = 1;   // 196608 B -> f32
        else if (in_sizes[0] == BB * 3 * NN * 2) isf32 = 0;   // 98304 B  -> bf16
    }
    if (isf32 < 0) {
        kdetect<<<1, 256, 0, stream>>>(p1, wsi);
    }

    // k1 stages its LDS tables directly from p1/p2 and (in tail blocks) builds the
    // global xyz table + folded weights consumed by k2. Two dispatches total.
    k1_knn<<<(BB * NN) / 4, 256, 0, stream>>>(p1, p2,
        d_in[2],  d_in[3],  d_in[4],  d_in[5],  d_in[6],  d_in[7],
        d_in[8],  d_in[9],  d_in[10], d_in[11], d_in[12], d_in[13],
        d_in[14], d_in[15], d_in[16], d_in[17], d_in[18], d_in[19],
        wsf, wsi, idxbuf, isf32);

    k2_mlp<<<(BB * NN) / 8, 512, 0, stream>>>(wsf, wsi, idxbuf, d_out, isf32);
}

// Round 19
// 223.825 us; speedup vs baseline: 1.0355x; 1.0355x over previous
//
#include <hip/hip_runtime.h>
#include <hip/hip_bf16.h>
#include <stdint.h>

#define BB 8
#define NN 2048

// ---- workspace layout ----
#define OFF_B1 272
#define OFF_B2 4432
#define OFF_B3 12688
#define IDX_BYTE_OFF 65536            // u16 idx[B][N][64] = 2 MiB (65536..2162688)
#define T_BASE   (65536 + 2*1024*1024)
// fragment-linear weight tables: lane L's 16B MFMA A-fragment at base + L*16 (conflict-free)
#define T1_OFF   T_BASE               // [4 tiles][64 lanes][8] bf16 = 4096 B
#define T2H_OFF  (T1_OFF + 4096)      // [4mt*2g][64][8] bf16 = 8192 B
#define T2L_OFF  (T2H_OFF + 8192)
#define T3H_OFF  (T2L_OFF + 8192)     // [8mt*2g][64][8] bf16 = 16384 B
#define T3L_OFF  (T3H_OFF + 16384)    // tables end at T_BASE+53248 = 2215936
#define XYZ_OFF  2228224              // f32x4 xyzs2[2][8][2048] = 512 KiB (2228224..2752512)
// LDS element-offsets (uint16) for k2's staged copy
#define L_T1   0
#define L_T2H  2048
#define L_T2L  6144
#define L_T3H  10240
#define L_T3L  18432
#define L_ELEMS 26624                 // 53248 B = 3328 uint4

typedef __attribute__((ext_vector_type(4))) float f32x4;
typedef __attribute__((ext_vector_type(8))) short s16x8;

__device__ __forceinline__ float ldany(const void* p, long i, int isf32) {
    if (isf32) return ((const float*)p)[i];
    uint32_t u = ((uint32_t)((const uint16_t*)p)[i]) << 16;
    float f; __builtin_memcpy(&f, &u, 4); return f;
}
__device__ __forceinline__ uint16_t f2bf(float f) {
    uint32_t u; __builtin_memcpy(&u, &f, 4);
    return (uint16_t)((u + 0x7FFFu + ((u >> 16) & 1u)) >> 16);
}
__device__ __forceinline__ float bf2f(uint16_t h) {
    uint32_t u = ((uint32_t)h) << 16;
    float f; __builtin_memcpy(&f, &u, 4); return f;
}
__device__ __forceinline__ uint32_t pk2(float a, float b) {
    __hip_bfloat162 h = __float22bfloat162_rn(make_float2(a, b));
    uint32_t u; __builtin_memcpy(&u, &h, 4); return u;
}
__device__ __forceinline__ s16x8 mk8(uint32_t a, uint32_t b, uint32_t c, uint32_t d) {
    uint32_t t[4] = {a, b, c, d}; s16x8 r; __builtin_memcpy(&r, t, 16); return r;
}
__device__ __forceinline__ float sane(float v) {
    return (v == v && v > -1e30f && v < 1e30f) ? v : 0.f;
}
__device__ __forceinline__ int mbcnt64(unsigned long long m) {
    return __builtin_amdgcn_mbcnt_hi((uint32_t)(m >> 32),
           __builtin_amdgcn_mbcnt_lo((uint32_t)m, 0));
}
__device__ __forceinline__ int kperm_pos(int kk) {
    int g = kk >> 5, c5 = kk & 31;
    int sub = (c5 >> 4) & 1, q = (c5 >> 2) & 3, r = c5 & 3;
    return 32 * g + 8 * q + 4 * sub + r;
}
// fragment-linear position for a (row o, within-row pos p) element of a 16-row-tile table.
__device__ __forceinline__ int fraglin(int o, int p) {
    int g = p >> 5, q = (p >> 3) & 3, e = p & 7;
    return ((((o >> 4) * 2 + g) * 64) + q * 16 + (o & 15)) * 8 + e;
}
// T1 (single 32-col table)
__device__ __forceinline__ int fraglin1(int o, int col) {
    int q = col >> 3, e = col & 7;
    return (((o >> 4) * 64) + q * 16 + (o & 15)) * 8 + e;
}

// ---------------- fallback-only: 1-block device dtype detect (used iff in_sizes is ambiguous) ----------------
__global__ void kdetect(const void* p1, int* wsi) {
    __shared__ int s_cnt;
    int t = threadIdx.x;
    if (t == 0) s_cnt = 0;
    __syncthreads();
    const uint16_t* u = (const uint16_t*)p1;
    int c = 0;
    for (int i = t; i < 4096; i += 256) {
        uint16_t x = u[i];
        uint32_t e = (x >> 7) & 0xFF;
        c += ((e >= 0x70 && e <= 0x84) || x == 0) ? 1 : 0;
    }
    atomicAdd(&s_cnt, c);
    __syncthreads();
    if (t == 0) wsi[0] = (s_cnt < 3686) ? 1 : 0;
}

// ---------------- K0XYZ: AoS {x,y,z,|p|^2} f32x4 table for both targets (query-invariant work) ----------------
__global__ void k0_xyz(const void* p1, const void* p2, float* wsf, const int* wsi, int isf32arg) {
    int isf32 = (isf32arg >= 0) ? isf32arg : wsi[0];
    int gid = blockIdx.x * 256 + threadIdx.x;        // 0..32767
    int tgt = gid >> 14, rem = gid & 16383;
    int b = rem >> 11, n = rem & 2047;
    const void* pp = tgt ? p2 : p1;
    long bb = (long)b * 3 * NN;
    float x = ldany(pp, bb + n,        isf32);
    float y = ldany(pp, bb + NN + n,   isf32);
    float z = ldany(pp, bb + 2*NN + n, isf32);
    f32x4 v;
    v[0] = x; v[1] = y; v[2] = z;
    v[3] = x * x + y * y + z * z;                    // same expression as prior inline s2
    ((f32x4*)((char*)wsf + XYZ_OFF))[gid] = v;
}

// ---- fold body: executed by blocks 0..54 of k1 as a cold tail ----
__device__ __forceinline__ void do_fold(int gid, int isf32,
                        const void* W1, const void* b1, const void* g1, const void* be1, const void* m1, const void* v1,
                        const void* W2, const void* b2, const void* g2, const void* be2, const void* m2, const void* v2,
                        const void* W3, const void* b3, const void* g3, const void* be3, const void* m3, const void* v3,
                        float* wsf) {
    uint16_t* t1  = (uint16_t*)((char*)wsf + T1_OFF);
    uint16_t* t2h = (uint16_t*)((char*)wsf + T2H_OFF);
    uint16_t* t2l = (uint16_t*)((char*)wsf + T2L_OFF);
    uint16_t* t3h = (uint16_t*)((char*)wsf + T3H_OFF);
    uint16_t* t3l = (uint16_t*)((char*)wsf + T3L_OFF);

    if (gid < 4096) {
        int o = gid >> 6, kk = gid & 63;
        float s = ldany(g2, o, isf32) * rsqrtf(ldany(v2, o, isf32) + 1e-3f);
        float w = ldany(W2, gid, isf32) * s;
        uint16_t wh = f2bf(w);
        int pos = fraglin(o, kperm_pos(kk));
        t2h[pos] = wh; t2l[pos] = f2bf(w - bf2f(wh));
    } else if (gid < 12288) {
        int e = gid - 4096;
        int o = e >> 6, kk = e & 63;
        float s = ldany(g3, o, isf32) * rsqrtf(ldany(v3, o, isf32) + 1e-3f);
        float w = ldany(W3, e, isf32) * s;
        uint16_t wh = f2bf(w);
        int pos = fraglin(o, kperm_pos(kk));
        t3h[pos] = wh; t3l[pos] = f2bf(w - bf2f(wh));
    } else if (gid < 12544) {
        int e = gid - 12288;
        int co = e >> 2, cc = e & 3;
        float s = ldany(g1, co, isf32) * rsqrtf(ldany(v1, co, isf32) + 1e-3f);
        float w = ldany(W1, co*4 + cc, isf32) * s;
        uint16_t wh = f2bf(w), wl = f2bf(w - bf2f(wh));
        t1[fraglin1(co, cc)]     = wh;
        t1[fraglin1(co, 4 + cc)] = wh;
        t1[fraglin1(co, 8 + cc)] = wl;
    } else if (gid < 13824) {
        int e = gid - 12544;
        int co = e / 20, k = e - co * 20;
        t1[fraglin1(co, 12 + k)] = 0;
    } else if (gid < 13888) {
        int o = gid - 13824;
        float s = ldany(g1, o, isf32) * rsqrtf(ldany(v1, o, isf32) + 1e-3f);
        wsf[OFF_B1 + o] = (ldany(b1, o, isf32) - ldany(m1, o, isf32)) * s + ldany(be1, o, isf32);
    } else if (gid < 13952) {
        int o = gid - 13888;
        float s = ldany(g2, o, isf32) * rsqrtf(ldany(v2, o, isf32) + 1e-3f);
        wsf[OFF_B2 + o] = (ldany(b2, o, isf32) - ldany(m2, o, isf32)) * s + ldany(be2, o, isf32);
    } else if (gid < 14080) {
        int o = gid - 13952;
        float s = ldany(g3, o, isf32) * rsqrtf(ldany(v3, o, isf32) + 1e-3f);
        wsf[OFF_B3 + o] = (ldany(b3, o, isf32) - ldany(m3, o, isf32)) * s + ldany(be3, o, isf32);
    }
}

// ---- one-target exact top-32 from an LDS-staged table: interpolated coarse bisection + compaction +
// single-ballot fine bisection for the exact bottom-32 SET (k2 is permutation-invariant).
// tb points to the block-shared LDS copy (byte-identical data -> identical d2 -> identical selection).
__device__ __forceinline__ void knn_target(const f32x4* __restrict__ tb, int lane,
                                           float qx, float qy, float qz, float s1,
                                           unsigned long long* sl, uint16_t* dst) {
    uint32_t kb[32];
    #pragma unroll
    for (int i = 0; i < 32; i++) {
        f32x4 P = tb[i * 64 + lane];
        float dot = qx * P[0] + qy * P[1] + qz * P[2];
        float d2  = fmaxf((s1 + P[3]) - 2.0f * dot, 0.0f);
        uint32_t bits; __builtin_memcpy(&bits, &d2, 4);
        kb[i] = bits;
    }

    // coarse: windowed bisection with interpolated probes, accept count in [32,64].
    uint32_t lo = 0u, hi = 0x7F800001u, tau = 0u;
    uint32_t mid = 0x3E800000u;   // 0.25f
    while (true) {
        int c = 0;
        #pragma unroll
        for (int i = 0; i < 32; i++) c += __builtin_popcountll(__ballot(kb[i] < mid));
        if (c >= 32 && c <= 64) { tau = mid; break; }
        if (c < 32) lo = mid; else hi = mid;
        if (hi - lo <= 1u) { tau = hi; break; }
        float mf; __builtin_memcpy(&mf, &mid, 4);
        float nf = mf * __powf(48.0f / (float)(c < 1 ? 1 : c), 0.6666667f);
        uint32_t nm; __builtin_memcpy(&nm, &nf, 4);
        if (!(nm > lo && nm < hi)) nm = lo + ((hi - lo) >> 1);
        mid = nm;
    }

    // compaction of survivors (kb < tau) into 64 LDS slots, key = (d2<<32)|idx
    sl[lane] = ~0ull;
    int basePos = 0;
    #pragma unroll
    for (int i = 0; i < 32; i++) {
        unsigned idxv = (unsigned)(i * 64 + lane);   // linear scan order (unified dtypes)
        bool pz = kb[i] < tau;
        unsigned long long m = __ballot(pz);
        int pos = basePos + mbcnt64(m);
        if (pz && pos < 64) sl[pos] = (((unsigned long long)kb[i]) << 32) | idxv;
        basePos += __builtin_popcountll(m);
    }
    unsigned long long key = sl[lane];

    // fine: single-ballot bisection for m* with |{key < m*}| == 32 exactly.
    int ns = basePos > 64 ? 64 : basePos;     // survivors actually in slots (>=32)
    unsigned long long mstar = ~0ull;         // ns==32: survivors ARE the set; skip fine
    if (ns != 32) {
        unsigned long long flo = 0ull;
        unsigned long long fhi = (((unsigned long long)tau) << 32) + 2048ull;
        float tauf; uint32_t tb2 = tau; __builtin_memcpy(&tauf, &tb2, 4);
        float g = tauf * __powf(32.5f / (float)ns, 0.6666667f);
        uint32_t gb; __builtin_memcpy(&gb, &g, 4);
        unsigned long long m0 = ((unsigned long long)gb) << 32;
        if (!(m0 > flo && m0 < fhi)) m0 = flo + ((fhi - flo) >> 1);
        unsigned long long midk = m0;
        while (true) {
            int f = __builtin_popcountll(__ballot(key < midk));
            if (f == 32) { mstar = midk; break; }
            if (f < 32) flo = midk; else fhi = midk;
            if (fhi - flo <= 1ull) { mstar = fhi; break; }
            midk = flo + ((fhi - flo) >> 1);
        }
    }

    bool sel = key < mstar;
    unsigned long long sm = __ballot(sel);
    if (sel) dst[mbcnt64(sm)] = (uint16_t)(key & 0x7FFu);
}

// ---------------- K1: dual-target top-32 — block-shared LDS table staging (all 4 waves share batch b)
// stage t1 -> sync -> knn(t1) -> sync -> stage t2 -> sync -> knn(t2). 34.8 KB LDS/block. ----
__launch_bounds__(256)
__global__ void k1_knn(const float* __restrict__ wsf_ro,
                       const void* W1, const void* b1, const void* g1, const void* be1, const void* m1, const void* v1,
                       const void* W2, const void* b2, const void* g2, const void* be2, const void* m2, const void* v2,
                       const void* W3, const void* b3, const void* g3, const void* be3, const void* m3, const void* v3,
                       float* wsf, const int* wsi, uint16_t* idxout, int isf32arg) {
    __shared__ f32x4 stab[2048];                    // 32 KB staged table (one target at a time)
    __shared__ unsigned long long smem[4 * 64];     // per-wave compaction slots

    int isf32 = (isf32arg >= 0) ? isf32arg : wsi[0];

    int t = threadIdx.x;
    int lane = threadIdx.x & 63;
    int wave = threadIdx.x >> 6;
    int qidx = blockIdx.x * 4 + wave;
    int b = qidx >> 11, n = qidx & 2047;            // 512 blocks/batch: all 4 waves share b

    const f32x4* xyz = (const f32x4*)((const char*)wsf_ro + XYZ_OFF);
    const f32x4* tb1 = xyz + (long)b * NN;          // target p1
    const f32x4* tb2 = xyz + (long)(8 + b) * NN;    // target p2

    f32x4 Q = tb1[n];
    float qx = Q[0], qy = Q[1], qz = Q[2], s1 = Q[3];

    unsigned long long* sl = smem + wave * 64;
    long obase = ((long)qidx) << 6;

    // stage target 1 (coalesced, 8 x f32x4 per thread)
    for (int j = t; j < 2048; j += 256) stab[j] = tb1[j];
    __syncthreads();
    knn_target(stab, lane, qx, qy, qz, s1, sl, idxout + obase);
    __syncthreads();

    // stage target 2
    for (int j = t; j < 2048; j += 256) stab[j] = tb2[j];
    __syncthreads();
    knn_target(stab, lane, qx, qy, qz, s1, sl, idxout + obase + 32);

    // cold tail: blocks 0..54 perform the parameter fold (identical gid mapping)
    if (blockIdx.x < 55) {
        int gid = blockIdx.x * 256 + t;
        do_fold(gid, isf32,
                W1, b1, g1, be1, m1, v1,
                W2, b2, g2, be2, m2, v2,
                W3, b3, g3, be3, m3, v3, wsf);
    }
}

// ---------------- K2: MFMA MLP — streaming conversion (R10-proven), frag-linear LDS, (512,2);
// neighbor/query coords gathered from the AoS table (1 x 16B gather vs 3 scattered loads) ----
__launch_bounds__(512, 2)
__global__ void k2_mlp(const float* __restrict__ wsf, const int* wsi,
                       const uint16_t* __restrict__ idxin, void* outp, int isf32arg) {
    __shared__ uint4 shw4[L_ELEMS / 8];

    {
        const uint4* src = (const uint4*)((const char*)wsf + T1_OFF);
        for (int i = threadIdx.x; i < L_ELEMS / 8; i += 512) shw4[i] = src[i];
    }
    __syncthreads();
    const uint16_t* shw = (const uint16_t*)shw4;
    const uint16_t* T1  = shw + L_T1;
    const uint16_t* T2H = shw + L_T2H;
    const uint16_t* T2L = shw + L_T2L;
    const uint16_t* T3H = shw + L_T3H;
    const uint16_t* T3L = shw + L_T3L;

    int isf32 = (isf32arg >= 0) ? isf32arg : wsi[0];
    int lane = threadIdx.x & 63;
    int wave = threadIdx.x >> 6;        // 0..7
    int c = lane & 15;
    int q = lane >> 4;
    int qidx = blockIdx.x * 8 + wave;   // 2048 blocks x 8 waves = 16384 queries
    int b = qidx >> 11, n = qidx & 2047;
    long base = (long)b * 3 * NN;

    const f32x4* xyz = (const f32x4*)((const char*)wsf + XYZ_OFF);

    f32x4 Q = xyz[(long)b * NN + n];
    float qx = sane(Q[0]), qy = sane(Q[1]), qz = sane(Q[2]);

    int idx = idxin[((long)qidx << 6) + lane] & 2047;
    int tgt = (lane < 32) ? 0 : 1;
    f32x4 P = xyz[(long)(tgt * 8 + b) * NN + idx];
    float nx = sane(P[0]), ny = sane(P[1]), nz = sane(P[2]);

    float r0 = nx - qx, r1 = ny - qy, r2 = nz - qz;
    float ss = fmaf(r0, r0, fmaf(r1, r1, r2 * r2));
    float dist = sqrtf(fmaxf(ss, 1e-12f));

    const float* B1 = wsf + OFF_B1;
    const float* B2 = wsf + OFF_B2;
    const float* B3 = wsf + OFF_B3;

    auto mkfrag = [](const f32x4& dlo, const f32x4& dhi) -> s16x8 {
        return mk8(pk2(fmaxf(dlo[0], 0.f), fmaxf(dlo[1], 0.f)),
                   pk2(fmaxf(dlo[2], 0.f), fmaxf(dlo[3], 0.f)),
                   pk2(fmaxf(dhi[0], 0.f), fmaxf(dhi[1], 0.f)),
                   pk2(fmaxf(dhi[2], 0.f), fmaxf(dhi[3], 0.f)));
    };

    // ---- layer 1: b1f (16 VGPR) + d1[4][4] (64) live; then convert ALL to fh (32), d1 dies ----
    s16x8 b1f[4];
    #pragma unroll
    for (int nt = 0; nt < 4; nt++) {
        int src = 16 * nt + c;
        float f0 = __shfl(r0, src, 64);
        float f1 = __shfl(r1, src, 64);
        float f2v = __shfl(r2, src, 64);
        float f3v = __shfl(dist, src, 64);
        uint16_t h0 = f2bf(f0), h1 = f2bf(f1), h2 = f2bf(f2v), h3 = f2bf(f3v);
        uint16_t l0 = f2bf(f0 - bf2f(h0)), l1 = f2bf(f1 - bf2f(h1));
        uint16_t l2 = f2bf(f2v - bf2f(h2)), l3 = f2bf(f3v - bf2f(h3));
        s16x8 v;
        bool qa = (q < 2);
        bool qb = (q == 0);
        v[0] = qa ? (short)h0 : (short)0;
        v[1] = qa ? (short)h1 : (short)0;
        v[2] = qa ? (short)h2 : (short)0;
        v[3] = qa ? (short)h3 : (short)0;
        v[4] = qb ? (short)l0 : (short)0;
        v[5] = qb ? (short)l1 : (short)0;
        v[6] = qb ? (short)l2 : (short)0;
        v[7] = qb ? (short)l3 : (short)0;
        b1f[nt] = v;
    }

    s16x8 fh[2][4];
    {
        f32x4 d1[4][4];
        #pragma unroll
        for (int mt = 0; mt < 4; mt++) {
            s16x8 a1 = *(const s16x8*)(T1 + (mt * 64 + lane) * 8);
            f32x4 bias = *(const f32x4*)(B1 + 16 * mt + 4 * q);
            #pragma unroll
            for (int nt = 0; nt < 4; nt++) {
                d1[mt][nt] = __builtin_amdgcn_mfma_f32_16x16x32_bf16(a1, b1f[nt], bias, 0, 0, 0);
            }
        }
        #pragma unroll
        for (int g = 0; g < 2; g++)
            #pragma unroll
            for (int nt = 0; nt < 4; nt++) fh[g][nt] = mkfrag(d1[2*g][nt], d1[2*g+1][nt]);
    }

    // ---- layer 2: fh (32) + d2[4][4] (64) + one weight pair (8) live ----
    s16x8 f3h[2][4];
    {
        f32x4 d2[4][4];
        #pragma unroll
        for (int mt = 0; mt < 4; mt++) {
            f32x4 bias = *(const f32x4*)(B2 + 16 * mt + 4 * q);
            #pragma unroll
            for (int nt = 0; nt < 4; nt++) d2[mt][nt] = bias;
        }
        #pragma unroll
        for (int g = 0; g < 2; g++) {
            #pragma unroll
            for (int mt = 0; mt < 4; mt++) {
                s16x8 ah = *(const s16x8*)(T2H + ((mt * 2 + g) * 64 + lane) * 8);
                s16x8 al = *(const s16x8*)(T2L + ((mt * 2 + g) * 64 + lane) * 8);
                #pragma unroll
                for (int nt = 0; nt < 4; nt++) {
                    f32x4 acc = d2[mt][nt];
                    acc = __builtin_amdgcn_mfma_f32_16x16x32_bf16(ah, fh[g][nt], acc, 0, 0, 0);
                    acc = __builtin_amdgcn_mfma_f32_16x16x32_bf16(al, fh[g][nt], acc, 0, 0, 0);
                    d2[mt][nt] = acc;
                }
            }
        }
        #pragma unroll
        for (int g = 0; g < 2; g++)
            #pragma unroll
            for (int nt = 0; nt < 4; nt++) f3h[g][nt] = mkfrag(d2[2*g][nt], d2[2*g+1][nt]);
    }

    // ---- layer 3: f3h (32) + acc[4] (16) + mx (4) live ----
    float mx[4] = {-1e30f, -1e30f, -1e30f, -1e30f};
    #pragma unroll
    for (int mt = 0; mt < 8; mt++) {
        f32x4 bias = *(const f32x4*)(B3 + 16 * mt + 4 * q);
        f32x4 acc[4];
        #pragma unroll
        for (int nt = 0; nt < 4; nt++) acc[nt] = bias;
        #pragma unroll
        for (int g = 0; g < 2; g++) {
            s16x8 ah = *(const s16x8*)(T3H + ((mt * 2 + g) * 64 + lane) * 8);
            s16x8 al = *(const s16x8*)(T3L + ((mt * 2 + g) * 64 + lane) * 8);
            #pragma unroll
            for (int nt = 0; nt < 4; nt++) {
                f32x4 a = acc[nt];
                a = __builtin_amdgcn_mfma_f32_16x16x32_bf16(ah, f3h[g][nt], a, 0, 0, 0);
                a = __builtin_amdgcn_mfma_f32_16x16x32_bf16(al, f3h[g][nt], a, 0, 0, 0);
                acc[nt] = a;
            }
        }
        #pragma unroll
        for (int nt = 0; nt < 4; nt++) {
            mx[nt] = fmaxf(mx[nt], fmaxf(fmaxf(acc[nt][0], acc[nt][1]), fmaxf(acc[nt][2], acc[nt][3])));
        }
    }

    #pragma unroll
    for (int nt = 0; nt < 4; nt++) {
        mx[nt] = fmaxf(mx[nt], __shfl_xor(mx[nt], 16, 64));
        mx[nt] = fmaxf(mx[nt], __shfl_xor(mx[nt], 32, 64));
        mx[nt] = fmaxf(mx[nt], 0.f);
    }
    float mall = fmaxf(fmaxf(mx[0], mx[1]), fmaxf(mx[2], mx[3]));
    #pragma unroll
    for (int m = 1; m < 16; m <<= 1) mall = fmaxf(mall, __shfl_xor(mall, m, 64));
    float e0 = __expf(mx[0] - mall), e1 = __expf(mx[1] - mall);
    float e2 = __expf(mx[2] - mall), e3 = __expf(mx[3] - mall);
    float s = e0 + e1 + e2 + e3;
    #pragma unroll
    for (int m = 1; m < 16; m <<= 1) s += __shfl_xor(s, m, 64);
    float eown = (q == 0) ? e0 : (q == 1) ? e1 : (q == 2) ? e2 : e3;
    float w = eown / s;

    float sx = w * nx, sy = w * ny, sz = w * nz;
    #pragma unroll
    for (int m = 1; m < 64; m <<= 1) {
        sx += __shfl_xor(sx, m, 64);
        sy += __shfl_xor(sy, m, 64);
        sz += __shfl_xor(sz, m, 64);
    }

    if (lane < 3) {
        float v = (lane == 0) ? sx : ((lane == 1) ? sy : sz);
        long oi = base + (long)lane * NN + n;
        if (isf32) {
            ((float*)outp)[oi] = v;
        } else {
            ((uint16_t*)outp)[oi] = f2bf(v);
        }
    }
}

extern "C" void kernel_launch(void* const* d_in, const int* in_sizes, int n_in,
                              void* d_out, int out_size, void* d_ws, size_t ws_size,
                              hipStream_t stream) {
    const void* p1 = d_in[0];
    const void* p2 = d_in[1];
    float* wsf = (float*)d_ws;
    int*   wsi = (int*)d_ws;
    uint16_t* idxbuf = (uint16_t*)((char*)d_ws + IDX_BYTE_OFF);

    // host-side dtype resolution from buffer byte sizes; -1 => device-detect fallback
    int isf32 = -1;
    if (in_sizes && n_in >= 1) {
        if (in_sizes[0] == BB * 3 * NN * 4)      isf32 = 1;   // 196608 B -> f32
        else if (in_sizes[0] == BB * 3 * NN * 2) isf32 = 0;   // 98304 B  -> bf16
    }
    if (isf32 < 0) {
        kdetect<<<1, 256, 0, stream>>>(p1, wsi);
    }

    // AoS {x,y,z,|p|^2} table for both targets (consumed by k1 and k2)
    k0_xyz<<<128, 256, 0, stream>>>(p1, p2, wsf, wsi, isf32);

    k1_knn<<<(BB * NN) / 4, 256, 0, stream>>>(wsf,
        d_in[2],  d_in[3],  d_in[4],  d_in[5],  d_in[6],  d_in[7],
        d_in[8],  d_in[9],  d_in[10], d_in[11], d_in[12], d_in[13],
        d_in[14], d_in[15], d_in[16], d_in[17], d_in[18], d_in[19],
        wsf, wsi, idxbuf, isf32);

    k2_mlp<<<(BB * NN) / 8, 512, 0, stream>>>(wsf, wsi, idxbuf, d_out, isf32);
}